// Round 1
// baseline (11.606 us; speedup 1.0000x reference)
//
#include <hip/hip_runtime.h>
#include <hip/hip_bf16.h>

#define BT_DEPTH 20
#define BT_NDIMS 128

// One block, 4 waves. Wave w computes logits l = w, w+4, ...
__global__ __launch_bounds__(256) void BinaryTree_18734647345500_kernel(
    const float* __restrict__ W,
    const int* __restrict__ v_j_idx,
    const int* __restrict__ u_k_idx,
    float* __restrict__ out)
{
    __shared__ float xs[BT_NDIMS];
    __shared__ float logits[BT_DEPTH + 1];

    const int tid  = threadIdx.x;
    const int wave = tid >> 6;
    const int lane = tid & 63;

    const int v = v_j_idx[0];
    const int u = u_k_idx[0];

    // x = W[v + 2^DEPTH - 1]  (leaf offset)
    const long long leaf = (long long)v + ((1 << BT_DEPTH) - 1);
    if (tid < BT_NDIMS) {
        xs[tid] = W[leaf * BT_NDIMS + tid];
    }
    __syncthreads();

    // path node at level l: ((u + 2^DEPTH) >> (DEPTH - l)) - 1
    const unsigned t = (unsigned)u + (1u << BT_DEPTH);

    for (int l = wave; l <= BT_DEPTH; l += 4) {
        const long long node = (long long)(t >> (BT_DEPTH - l)) - 1;
        const float* __restrict__ row = W + node * (long long)BT_NDIMS;

        // each lane handles 2 dims -> 64 lanes * 2 = 128
        const float2 rv = *(const float2*)(row + lane * 2);
        const float2 xv = *(const float2*)(&xs[lane * 2]);
        float s = rv.x * xv.x + rv.y * xv.y;

        // 64-lane butterfly reduce
        s += __shfl_xor(s, 32, 64);
        s += __shfl_xor(s, 16, 64);
        s += __shfl_xor(s,  8, 64);
        s += __shfl_xor(s,  4, 64);
        s += __shfl_xor(s,  2, 64);
        s += __shfl_xor(s,  1, 64);

        if (lane == 0) logits[l] = s;
    }
    __syncthreads();

    if (tid == 0) {
        float p = 1.0f;
        #pragma unroll
        for (int l = 0; l <= BT_DEPTH; ++l) {
            const float z = logits[l];
            p *= 1.0f / (1.0f + expf(-z));
        }
        out[0] = p;
    }
}

extern "C" void kernel_launch(void* const* d_in, const int* in_sizes, int n_in,
                              void* d_out, int out_size, void* d_ws, size_t ws_size,
                              hipStream_t stream) {
    const float* W   = (const float*)d_in[0];
    const int*   vj  = (const int*)d_in[1];
    const int*   uk  = (const int*)d_in[2];
    float*       out = (float*)d_out;

    hipLaunchKernelGGL(BinaryTree_18734647345500_kernel,
                       dim3(1), dim3(256), 0, stream,
                       W, vj, uk, out);
}

// Round 2
// 9.339 us; speedup vs baseline: 1.2427x; 1.2427x over previous
//
#include <hip/hip_runtime.h>
#include <hip/hip_bf16.h>

#define BT_DEPTH 20
#define BT_NDIMS 128

// One block, 4 waves. Wave w owns levels l = w, w+4, ... (6 levels for wave 0,
// 5 for waves 1..3). No LDS staging of x: each lane loads its own float2 of the
// leaf row, so ALL loads (leaf + path rows) issue in one latency round-trip
// right after the index load resolves. Each wave folds its levels into a
// partial product of sigmoids; one barrier; thread 0 multiplies 4 partials.
__global__ __launch_bounds__(256) void BinaryTree_18734647345500_kernel(
    const float* __restrict__ W,
    const int* __restrict__ v_j_idx,
    const int* __restrict__ u_k_idx,
    float* __restrict__ out)
{
    __shared__ float pp[4];

    const int tid  = threadIdx.x;
    const int wave = tid >> 6;
    const int lane = tid & 63;

    const int v = v_j_idx[0];
    const int u = u_k_idx[0];

    // leaf row of x: W[v + 2^DEPTH - 1]
    const long long leaf = (long long)v + ((1 << BT_DEPTH) - 1);
    const unsigned  t    = (unsigned)u + (1u << BT_DEPTH);

    // This lane's 2 dims of x (no LDS, no barrier).
    const float2 xv = *(const float2*)(W + leaf * BT_NDIMS + lane * 2);

    // Issue all path-row loads back-to-back (unrolled; loads independent).
    float z[6];
    #pragma unroll
    for (int i = 0; i < 6; ++i) {
        const int l = wave + 4 * i;
        // For waves 1..3, i==5 gives l>20: clamp shift to 0 -> loads the
        // (valid) leaf node row; result is discarded below.
        const int shift = (l <= BT_DEPTH) ? (BT_DEPTH - l) : 0;
        const long long node = (long long)(t >> shift) - 1;
        const float2 rv = *(const float2*)(W + node * (long long)BT_NDIMS + lane * 2);
        z[i] = rv.x * xv.x + rv.y * xv.y;
    }

    // Reduce each level's partial across the 64-lane wave.
    #pragma unroll
    for (int i = 0; i < 6; ++i) {
        float s = z[i];
        s += __shfl_xor(s, 32, 64);
        s += __shfl_xor(s, 16, 64);
        s += __shfl_xor(s,  8, 64);
        s += __shfl_xor(s,  4, 64);
        s += __shfl_xor(s,  2, 64);
        s += __shfl_xor(s,  1, 64);
        z[i] = s;
    }

    if (lane == 0) {
        const int nlev = (wave == 0) ? 6 : 5;
        float p = 1.0f;
        #pragma unroll
        for (int i = 0; i < 6; ++i) {
            if (i < nlev) p *= 1.0f / (1.0f + expf(-z[i]));
        }
        pp[wave] = p;
    }
    __syncthreads();

    if (tid == 0) {
        out[0] = pp[0] * pp[1] * pp[2] * pp[3];
    }
}

extern "C" void kernel_launch(void* const* d_in, const int* in_sizes, int n_in,
                              void* d_out, int out_size, void* d_ws, size_t ws_size,
                              hipStream_t stream) {
    const float* W   = (const float*)d_in[0];
    const int*   vj  = (const int*)d_in[1];
    const int*   uk  = (const int*)d_in[2];
    float*       out = (float*)d_out;

    hipLaunchKernelGGL(BinaryTree_18734647345500_kernel,
                       dim3(1), dim3(256), 0, stream,
                       W, vj, uk, out);
}